// Round 8
// baseline (162.942 us; speedup 1.0000x reference)
//
#include <hip/hip_runtime.h>

// Problem constants
#define B_SZ   8
#define T_SEQ  2048
#define C_DIM  1024
#define H_DIM  128

typedef _Float16 half8   __attribute__((ext_vector_type(8)));
typedef _Float16 half4_t __attribute__((ext_vector_type(4)));
typedef float    f32x4   __attribute__((ext_vector_type(4)));

#define MFMA(a, b, c) __builtin_amdgcn_mfma_f32_16x16x32_f16(a, b, c, 0, 0, 0)

// ---------------------------------------------------------------------------
// prep: W [C][H] fp32 -> WT [H][C] half (3 weights).  grid (512,3) x 256
// ---------------------------------------------------------------------------
__global__ __launch_bounds__(256) void prep_kernel(
    const float* __restrict__ Wk, const float* __restrict__ Wq,
    const float* __restrict__ Wv, _Float16* __restrict__ WT_all)
{
    const int w = blockIdx.y;
    const float* W = (w == 0) ? Wk : (w == 1) ? Wq : Wv;
    _Float16* dst = WT_all + (size_t)w * (C_DIM * H_DIM);
    int tid = blockIdx.x * 256 + threadIdx.x;
    int c = tid >> 7;
    int h = tid & (H_DIM - 1);
    dst[(size_t)h * C_DIM + c] = (_Float16)W[tid];
}

// ---------------------------------------------------------------------------
// proj (FUSED): one block computes k, q, vT for its 32 m-rows -> x is read
// from HBM exactly once (R7 counter showed 102 MB fetched vs 76 MB ideal:
// the 3-way weight split re-read x ~1.6x). grid 512 x 256 (2 blocks/CU,
// LDS 59904 B). Register-prefetch pipeline: next tile's global loads are
// issued into regs right after the barrier and stay IN FLIGHT through the
// whole MFMA phase (regs->LDS only after compute) -- overlaps the ~900cyc
// HBM latency with compute instead of draining it at the barrier.
// ---------------------------------------------------------------------------
__global__ __launch_bounds__(256, 2) void proj_kernel(
    const float* __restrict__ x, const _Float16* __restrict__ WT_all,
    _Float16* __restrict__ qo, _Float16* __restrict__ ko, _Float16* __restrict__ vT)
{
    __shared__ _Float16 xs [32][72];        //  4608 B
    __shared__ _Float16 wsh[3][128][72];    // 55296 B  (59904 total)

    const int m0 = blockIdx.x * 32;
    const int t  = threadIdx.x;
    const int wave = t >> 6, lane = t & 63;
    const int quad = lane >> 4, l15 = lane & 15;
    const int wm = (wave >> 1) * 16;    // 0 or 16
    const int wn = (wave & 1) * 64;     // 0 or 64

    // staging coords
    const int xrow = t >> 4, xcol = (t & 15) * 4;   // 2 passes x (16 rows x 16 segs)
    const int wrow = t >> 3, wcol = (t & 7) * 8;    // 4 passes x (32 rows x 8 segs)

    f32x4 acc[3][4] = {};

    float4 xr[2];
    half8  wr[3][4];

    // ---- stage_load(k0): global -> regs ----
    auto stage_load = [&](int k0) {
        #pragma unroll
        for (int p = 0; p < 2; ++p)
            xr[p] = *(const float4*)(x + (size_t)(m0 + p * 16 + xrow) * C_DIM + k0 + xcol);
        #pragma unroll
        for (int w = 0; w < 3; ++w)
            #pragma unroll
            for (int p = 0; p < 4; ++p)
                wr[w][p] = *(const half8*)(WT_all + (size_t)w * (C_DIM * H_DIM)
                                           + (size_t)(p * 32 + wrow) * C_DIM + k0 + wcol);
    };
    // ---- stage_write(): regs -> LDS ----
    auto stage_write = [&]() {
        #pragma unroll
        for (int p = 0; p < 2; ++p) {
            half4_t hv = { (_Float16)xr[p].x, (_Float16)xr[p].y,
                           (_Float16)xr[p].z, (_Float16)xr[p].w };
            *(half4_t*)(&xs[p * 16 + xrow][xcol]) = hv;
        }
        #pragma unroll
        for (int w = 0; w < 3; ++w)
            #pragma unroll
            for (int p = 0; p < 4; ++p)
                *(half8*)(&wsh[w][p * 32 + wrow][wcol]) = wr[w][p];
    };
    // ---- compute(): MFMAs on current LDS tile ----
    auto compute = [&]() {
        #pragma unroll
        for (int kb = 0; kb < 2; ++kb) {
            half8 af = *(const half8*)(&xs[wm + l15][kb * 32 + quad * 8]);
            #pragma unroll
            for (int w = 0; w < 3; ++w) {
                #pragma unroll
                for (int j = 0; j < 4; ++j) {
                    half8 bf = *(const half8*)(&wsh[w][wn + j * 16 + l15][kb * 32 + quad * 8]);
                    acc[w][j] = MFMA(af, bf, acc[w][j]);
                }
            }
        }
    };

    stage_load(0);
    stage_write();
    for (int it = 1; it <= 16; ++it) {
        __syncthreads();                   // LDS tile (it-1) visible
        if (it < 16) stage_load(it * 64);  // prefetch next tile into regs
        compute();                         // consume tile (it-1)
        if (it < 16) {
            __syncthreads();               // all consumers done
            stage_write();                 // regs -> LDS (waits vmcnt here)
        }
    }

    // epilogue
    const int row = m0 + wm + quad * 4;
    #pragma unroll
    for (int w = 0; w < 2; ++w) {
        _Float16* outN = (w == 0) ? ko : qo;
        #pragma unroll
        for (int j = 0; j < 4; ++j) {
            int col = wn + j * 16 + l15;
            #pragma unroll
            for (int r = 0; r < 4; ++r)
                outN[(size_t)(row + r) * H_DIM + col] = (_Float16)acc[w][j][r];
        }
    }
    {
        int bb = row >> 11, tp = row & (T_SEQ - 1);
        #pragma unroll
        for (int j = 0; j < 4; ++j) {
            int h = wn + j * 16 + l15;
            half4_t hv = { (_Float16)acc[2][j][0], (_Float16)acc[2][j][1],
                           (_Float16)acc[2][j][2], (_Float16)acc[2][j][3] };
            *(half4_t*)(vT + ((size_t)bb * H_DIM + h) * T_SEQ + tp) = hv;
        }
    }
}

// ---------------------------------------------------------------------------
// attn: 4 waves/block, qtile 64, kv tile 64, kv-chunk 512. (unchanged R7)
// K and V staged in LDS; no-max softmax; XCD-batch affinity; heavy-first.
// ---------------------------------------------------------------------------
__global__ __launch_bounds__(256, 3) void attn_kernel(
    const _Float16* __restrict__ q, const _Float16* __restrict__ k,
    const _Float16* __restrict__ vT,
    _Float16* __restrict__ pO, float* __restrict__ ml, float* __restrict__ out)
{
    __shared__ _Float16 ks [64][136];    // 17408 B
    __shared__ _Float16 vts[128][72];    // 18432 B
    __shared__ _Float16 ps [4][16][72];  //  9216 B   (total 45056)

    const int n = blockIdx.x;
    const int b = n & 7;
    const int u = n >> 3;                // 0..79, heavy-first

    int qt = 31, c = 0;
    {
        int acc = 0;
        #pragma unroll 1
        while (true) {
            int nch = (qt >> 3) + 1;
            if (u < acc + nch) { c = u - acc; break; }
            acc += nch; --qt;
        }
    }
    const bool partial = (qt >= 8);

    const int kt0 = c * 8;
    const int kt1 = min(qt, c * 8 + 7);

    const int t = threadIdx.x;
    const int wave = t >> 6, lane = t & 63;
    const int quad = lane >> 4, l15 = lane & 15;
    const int qrow0 = qt * 64 + wave * 16;

    const _Float16* qb = q  + (size_t)b * T_SEQ * H_DIM;
    const _Float16* kp = k  + (size_t)b * T_SEQ * H_DIM;
    const _Float16* vp = vT + (size_t)b * H_DIM * T_SEQ;

    half8 aq[4];
    #pragma unroll
    for (int i = 0; i < 4; ++i) {
        half8 v = *(const half8*)(qb + (size_t)(qrow0 + l15) * H_DIM + i * 32 + quad * 8);
        #pragma unroll
        for (int j = 0; j < 8; ++j) v[j] = v[j] * (_Float16)0.088388347648318447f;
        aq[i] = v;
    }

    f32x4 accO[8] = {};
    float lrun[4] = {0.0f, 0.0f, 0.0f, 0.0f};

    const int krow = t >> 4, kseg = t & 15;
    const int vrow = t >> 3, vseg = t & 7;

    for (int kt = kt0; kt <= kt1; ++kt) {
        const int kv0 = kt * 64;
        __syncthreads();
        #pragma unroll
        for (int p = 0; p < 4; ++p) {
            int row = p * 16 + krow;
            *(half8*)(&ks[row][kseg * 8]) =
                *(const half8*)(kp + (size_t)(kv0 + row) * H_DIM + kseg * 8);
        }
        #pragma unroll
        for (int p = 0; p < 4; ++p) {
            int h = p * 32 + vrow;
            *(half8*)(&vts[h][vseg * 8]) =
                *(const half8*)(vp + (size_t)h * T_SEQ + kv0 + vseg * 8);
        }
        __syncthreads();

        f32x4 sacc[4] = {};
        #pragma unroll
        for (int kbi = 0; kbi < 4; ++kbi) {
            #pragma unroll
            for (int nt = 0; nt < 4; ++nt) {
                half8 bf = *(const half8*)(&ks[nt * 16 + l15][kbi * 32 + quad * 8]);
                sacc[nt] = MFMA(aq[kbi], bf, sacc[nt]);
            }
        }

        if (kv0 + 63 > qrow0) {
            #pragma unroll
            for (int nt = 0; nt < 4; ++nt) {
                int key = kv0 + nt * 16 + l15;
                #pragma unroll
                for (int r = 0; r < 4; ++r) {
                    int qr = qrow0 + quad * 4 + r;
                    if (key > qr) sacc[nt][r] = -1.0e30f;
                }
            }
        }

        #pragma unroll
        for (int nt = 0; nt < 4; ++nt)
            #pragma unroll
            for (int r = 0; r < 4; ++r) {
                float p = __expf(sacc[nt][r]);
                lrun[r] += p;
                ps[wave][quad * 4 + r][nt * 16 + l15] = (_Float16)p;
            }

        half8 pf0 = *(const half8*)(&ps[wave][l15][quad * 8]);
        half8 pf1 = *(const half8*)(&ps[wave][l15][32 + quad * 8]);
        #pragma unroll
        for (int nt = 0; nt < 8; ++nt) {
            half8 vf0 = *(const half8*)(&vts[nt * 16 + l15][quad * 8]);
            half8 vf1 = *(const half8*)(&vts[nt * 16 + l15][32 + quad * 8]);
            accO[nt] = MFMA(pf0, vf0, accO[nt]);
            accO[nt] = MFMA(pf1, vf1, accO[nt]);
        }
    }

    #pragma unroll
    for (int r = 0; r < 4; ++r) {
        lrun[r] += __shfl_xor(lrun[r], 1);
        lrun[r] += __shfl_xor(lrun[r], 2);
        lrun[r] += __shfl_xor(lrun[r], 4);
        lrun[r] += __shfl_xor(lrun[r], 8);
    }

    if (partial) {
        const int pid = b * 72 + u;
        const int urow = wave * 16 + quad * 4;
        #pragma unroll
        for (int nt = 0; nt < 8; ++nt)
            #pragma unroll
            for (int r = 0; r < 4; ++r)
                pO[(size_t)pid * 8192 + (urow + r) * 128 + nt * 16 + l15]
                    = (_Float16)accO[nt][r];
        if (l15 == 0) {
            #pragma unroll
            for (int r = 0; r < 4; ++r)
                ml[(size_t)pid * 64 + urow + r] = lrun[r];
        }
    } else {
        float invl[4];
        #pragma unroll
        for (int r = 0; r < 4; ++r) invl[r] = 1.0f / lrun[r];
        #pragma unroll
        for (int nt = 0; nt < 8; ++nt)
            #pragma unroll
            for (int r = 0; r < 4; ++r)
                out[((size_t)b * T_SEQ + qrow0 + quad * 4 + r) * H_DIM + nt * 16 + l15]
                    = accO[nt][r] * invl[r];
    }
}

// ---------------------------------------------------------------------------
// combine: out = (sum_c pO[c]) / (sum_c l[c]); nc = qt/8+1 in 2..4. (unchanged)
// ---------------------------------------------------------------------------
__global__ __launch_bounds__(256) void attn_combine(
    const _Float16* __restrict__ pO, const float* __restrict__ ml,
    float* __restrict__ out)
{
    const int n  = blockIdx.x;
    const int b  = n & 7;
    const int m  = n >> 3;               // 0..95
    const int rg = m & 3;
    const int qt = 8 + (m >> 2);         // 8..31
    const int nc = (qt >> 3) + 1;        // 2..4

    int u0 = 0;
    #pragma unroll 1
    for (int q2 = 31; q2 > qt; --q2) u0 += (q2 >> 3) + 1;
    const size_t pid0 = (size_t)b * 72 + u0;

    const int t   = threadIdx.x;
    const int row = rg * 16 + (t >> 4);
    const int h   = (t & 15) * 8;

    float lsum = 0.0f;
    #pragma unroll 1
    for (int c = 0; c < nc; ++c)
        lsum += ml[(pid0 + c) * 64 + row];

    float acc[8] = {};
    #pragma unroll 1
    for (int c = 0; c < nc; ++c) {
        half8 po = *(const half8*)(pO + (pid0 + c) * 8192 + row * 128 + h);
        #pragma unroll
        for (int j = 0; j < 8; ++j) acc[j] += (float)po[j];
    }

    const float inv = 1.0f / lsum;
    float* op = out + ((size_t)b * T_SEQ + qt * 64 + row) * H_DIM + h;
    f32x4 o0 = { acc[0] * inv, acc[1] * inv, acc[2] * inv, acc[3] * inv };
    f32x4 o1 = { acc[4] * inv, acc[5] * inv, acc[6] * inv, acc[7] * inv };
    *(f32x4*)(op)     = o0;
    *(f32x4*)(op + 4) = o1;
}

// ---------------------------------------------------------------------------
extern "C" void kernel_launch(void* const* d_in, const int* in_sizes, int n_in,
                              void* d_out, int out_size, void* d_ws, size_t ws_size,
                              hipStream_t stream)
{
    const float* x  = (const float*)d_in[0];
    const float* Wk = (const float*)d_in[1];
    const float* Wq = (const float*)d_in[2];
    const float* Wv = (const float*)d_in[3];
    float* out = (float*)d_out;

    _Float16* ws = (_Float16*)d_ws;
    const size_t NQKV = (size_t)B_SZ * T_SEQ * H_DIM;          // 2,097,152
    _Float16* q_ws  = ws;
    _Float16* k_ws  = ws + NQKV;
    _Float16* vT_ws = ws + 2 * NQKV;
    _Float16* wt_ws = ws + 3 * NQKV;                           // 3*C*H halfs
    _Float16* pO_ws = wt_ws + 3 * (size_t)(C_DIM * H_DIM);     // 576 units * 8192 halfs
    float*    ml_ws = (float*)(pO_ws + (size_t)576 * 8192);    // 576 * 64 floats

    prep_kernel <<<dim3(512, 3), 256, 0, stream>>>(Wk, Wq, Wv, wt_ws);
    proj_kernel <<<512, 256, 0, stream>>>(x, wt_ws, q_ws, k_ws, vT_ws);
    attn_kernel <<<640, 256, 0, stream>>>(q_ws, k_ws, vT_ws, pO_ws, ml_ws, out);
    attn_combine<<<768, 256, 0, stream>>>(pO_ws, ml_ws, out);
}

// Round 9
// 150.149 us; speedup vs baseline: 1.0852x; 1.0852x over previous
//
#include <hip/hip_runtime.h>

// Problem constants
#define B_SZ   8
#define T_SEQ  2048
#define C_DIM  1024
#define H_DIM  128

typedef _Float16 half8   __attribute__((ext_vector_type(8)));
typedef _Float16 half4_t __attribute__((ext_vector_type(4)));
typedef float    f32x4   __attribute__((ext_vector_type(4)));

#define MFMA(a, b, c) __builtin_amdgcn_mfma_f32_16x16x32_f16(a, b, c, 0, 0, 0)

// ---------------------------------------------------------------------------
// prep: W [C][H] fp32 -> WT [H][C] half (3 weights).  grid (512,3) x 256
// ---------------------------------------------------------------------------
__global__ __launch_bounds__(256) void prep_kernel(
    const float* __restrict__ Wk, const float* __restrict__ Wq,
    const float* __restrict__ Wv, _Float16* __restrict__ WT_all)
{
    const int w = blockIdx.y;
    const float* W = (w == 0) ? Wk : (w == 1) ? Wq : Wv;
    _Float16* dst = WT_all + (size_t)w * (C_DIM * H_DIM);
    int tid = blockIdx.x * 256 + threadIdx.x;
    int c = tid >> 7;
    int h = tid & (H_DIM - 1);
    dst[(size_t)h * C_DIM + c] = (_Float16)W[tid];
}

// ---------------------------------------------------------------------------
// proj: out[m][n] = sum_k x[m][k]*W[k][n], M=16384 K=1024 N=128.
// R7 structure, TRANSPOSED GRID (256,3): n = w*256 + m_idx, so the 3 blocks
// sharing an x stripe are 256 apart in dispatch order -> same (n mod 8) ->
// SAME XCD, and with all 768 blocks co-resident (3/CU) they run concurrently
// -> 2 of 3 x-stripe reads hit the XCD-local L2 instead of HBM/L3.
// (R7 grid (3,256) scattered each trio over 3 XCDs: 196 MB demand -> 102 MB
// HBM. R8's fusion fixed traffic but broke the pipeline; this fixes traffic
// by placement with zero structural change.)
// w==0 -> k [B*T][H], w==1 -> q, w==2 -> vT [B][H][T] (transposed).
// ---------------------------------------------------------------------------
__global__ __launch_bounds__(256, 3) void proj_kernel(
    const float* __restrict__ x, const _Float16* __restrict__ WT_all,
    _Float16* __restrict__ q, _Float16* __restrict__ k, _Float16* __restrict__ vT)
{
    __shared__ _Float16 xs [64][72];
    __shared__ _Float16 wsh[128][72];

    const int w  = blockIdx.y;
    const int m0 = blockIdx.x * 64;
    const _Float16* WT = WT_all + (size_t)w * (C_DIM * H_DIM);

    const int t    = threadIdx.x;
    const int wave = t >> 6, lane = t & 63;
    const int quad = lane >> 4, l15 = lane & 15;
    const int wm = (wave >> 1) * 32;
    const int wn = (wave & 1) * 64;

    f32x4 acc[2][4] = {};

    for (int k0 = 0; k0 < C_DIM; k0 += 64) {
        __syncthreads();
        {
            const int row_ = t >> 4, col = (t & 15) * 4;
            #pragma unroll
            for (int p = 0; p < 4; ++p) {
                int row = p * 16 + row_;
                float4 f = *(const float4*)(x + (size_t)(m0 + row) * C_DIM + k0 + col);
                half4_t hv = { (_Float16)f.x, (_Float16)f.y, (_Float16)f.z, (_Float16)f.w };
                *(half4_t*)(&xs[row][col]) = hv;
            }
        }
        {
            const int row_ = t >> 3, col = (t & 7) * 8;
            #pragma unroll
            for (int p = 0; p < 4; ++p) {
                int row = p * 32 + row_;
                *(half8*)(&wsh[row][col]) = *(const half8*)(WT + (size_t)row * C_DIM + k0 + col);
            }
        }
        __syncthreads();
        #pragma unroll
        for (int kb = 0; kb < 2; ++kb) {
            half8 af[2], bf[4];
            #pragma unroll
            for (int i = 0; i < 2; ++i)
                af[i] = *(const half8*)(&xs[wm + i * 16 + l15][kb * 32 + quad * 8]);
            #pragma unroll
            for (int j = 0; j < 4; ++j)
                bf[j] = *(const half8*)(&wsh[wn + j * 16 + l15][kb * 32 + quad * 8]);
            #pragma unroll
            for (int i = 0; i < 2; ++i)
                #pragma unroll
                for (int j = 0; j < 4; ++j)
                    acc[i][j] = MFMA(af[i], bf[j], acc[i][j]);
        }
    }

    if (w != 2) {
        _Float16* outN = (w == 0) ? k : q;
        #pragma unroll
        for (int i = 0; i < 2; ++i) {
            int row = m0 + wm + i * 16 + quad * 4;
            #pragma unroll
            for (int j = 0; j < 4; ++j) {
                int col = wn + j * 16 + l15;
                #pragma unroll
                for (int r = 0; r < 4; ++r)
                    outN[(size_t)(row + r) * H_DIM + col] = (_Float16)acc[i][j][r];
            }
        }
    } else {
        #pragma unroll
        for (int i = 0; i < 2; ++i) {
            int grow = m0 + wm + i * 16 + quad * 4;
            int bb = grow >> 11, tp = grow & (T_SEQ - 1);
            #pragma unroll
            for (int j = 0; j < 4; ++j) {
                int h = wn + j * 16 + l15;
                half4_t hv = { (_Float16)acc[i][j][0], (_Float16)acc[i][j][1],
                               (_Float16)acc[i][j][2], (_Float16)acc[i][j][3] };
                *(half4_t*)(vT + ((size_t)bb * H_DIM + h) * T_SEQ + tp) = hv;
            }
        }
    }
}

// ---------------------------------------------------------------------------
// attn: 4 waves/block, qtile 64, kv tile 64, kv-chunk 512. (unchanged R7)
// K and V staged in LDS; no-max softmax; XCD-batch affinity; heavy-first.
// ---------------------------------------------------------------------------
__global__ __launch_bounds__(256, 3) void attn_kernel(
    const _Float16* __restrict__ q, const _Float16* __restrict__ k,
    const _Float16* __restrict__ vT,
    _Float16* __restrict__ pO, float* __restrict__ ml, float* __restrict__ out)
{
    __shared__ _Float16 ks [64][136];    // 17408 B
    __shared__ _Float16 vts[128][72];    // 18432 B
    __shared__ _Float16 ps [4][16][72];  //  9216 B   (total 45056)

    const int n = blockIdx.x;
    const int b = n & 7;
    const int u = n >> 3;                // 0..79, heavy-first

    int qt = 31, c = 0;
    {
        int acc = 0;
        #pragma unroll 1
        while (true) {
            int nch = (qt >> 3) + 1;
            if (u < acc + nch) { c = u - acc; break; }
            acc += nch; --qt;
        }
    }
    const bool partial = (qt >= 8);

    const int kt0 = c * 8;
    const int kt1 = min(qt, c * 8 + 7);

    const int t = threadIdx.x;
    const int wave = t >> 6, lane = t & 63;
    const int quad = lane >> 4, l15 = lane & 15;
    const int qrow0 = qt * 64 + wave * 16;

    const _Float16* qb = q  + (size_t)b * T_SEQ * H_DIM;
    const _Float16* kp = k  + (size_t)b * T_SEQ * H_DIM;
    const _Float16* vp = vT + (size_t)b * H_DIM * T_SEQ;

    half8 aq[4];
    #pragma unroll
    for (int i = 0; i < 4; ++i) {
        half8 v = *(const half8*)(qb + (size_t)(qrow0 + l15) * H_DIM + i * 32 + quad * 8);
        #pragma unroll
        for (int j = 0; j < 8; ++j) v[j] = v[j] * (_Float16)0.088388347648318447f;
        aq[i] = v;
    }

    f32x4 accO[8] = {};
    float lrun[4] = {0.0f, 0.0f, 0.0f, 0.0f};

    const int krow = t >> 4, kseg = t & 15;
    const int vrow = t >> 3, vseg = t & 7;

    for (int kt = kt0; kt <= kt1; ++kt) {
        const int kv0 = kt * 64;
        __syncthreads();
        #pragma unroll
        for (int p = 0; p < 4; ++p) {
            int row = p * 16 + krow;
            *(half8*)(&ks[row][kseg * 8]) =
                *(const half8*)(kp + (size_t)(kv0 + row) * H_DIM + kseg * 8);
        }
        #pragma unroll
        for (int p = 0; p < 4; ++p) {
            int h = p * 32 + vrow;
            *(half8*)(&vts[h][vseg * 8]) =
                *(const half8*)(vp + (size_t)h * T_SEQ + kv0 + vseg * 8);
        }
        __syncthreads();

        f32x4 sacc[4] = {};
        #pragma unroll
        for (int kbi = 0; kbi < 4; ++kbi) {
            #pragma unroll
            for (int nt = 0; nt < 4; ++nt) {
                half8 bf = *(const half8*)(&ks[nt * 16 + l15][kbi * 32 + quad * 8]);
                sacc[nt] = MFMA(aq[kbi], bf, sacc[nt]);
            }
        }

        if (kv0 + 63 > qrow0) {
            #pragma unroll
            for (int nt = 0; nt < 4; ++nt) {
                int key = kv0 + nt * 16 + l15;
                #pragma unroll
                for (int r = 0; r < 4; ++r) {
                    int qr = qrow0 + quad * 4 + r;
                    if (key > qr) sacc[nt][r] = -1.0e30f;
                }
            }
        }

        #pragma unroll
        for (int nt = 0; nt < 4; ++nt)
            #pragma unroll
            for (int r = 0; r < 4; ++r) {
                float p = __expf(sacc[nt][r]);
                lrun[r] += p;
                ps[wave][quad * 4 + r][nt * 16 + l15] = (_Float16)p;
            }

        half8 pf0 = *(const half8*)(&ps[wave][l15][quad * 8]);
        half8 pf1 = *(const half8*)(&ps[wave][l15][32 + quad * 8]);
        #pragma unroll
        for (int nt = 0; nt < 8; ++nt) {
            half8 vf0 = *(const half8*)(&vts[nt * 16 + l15][quad * 8]);
            half8 vf1 = *(const half8*)(&vts[nt * 16 + l15][32 + quad * 8]);
            accO[nt] = MFMA(pf0, vf0, accO[nt]);
            accO[nt] = MFMA(pf1, vf1, accO[nt]);
        }
    }

    #pragma unroll
    for (int r = 0; r < 4; ++r) {
        lrun[r] += __shfl_xor(lrun[r], 1);
        lrun[r] += __shfl_xor(lrun[r], 2);
        lrun[r] += __shfl_xor(lrun[r], 4);
        lrun[r] += __shfl_xor(lrun[r], 8);
    }

    if (partial) {
        const int pid = b * 72 + u;
        const int urow = wave * 16 + quad * 4;
        #pragma unroll
        for (int nt = 0; nt < 8; ++nt)
            #pragma unroll
            for (int r = 0; r < 4; ++r)
                pO[(size_t)pid * 8192 + (urow + r) * 128 + nt * 16 + l15]
                    = (_Float16)accO[nt][r];
        if (l15 == 0) {
            #pragma unroll
            for (int r = 0; r < 4; ++r)
                ml[(size_t)pid * 64 + urow + r] = lrun[r];
        }
    } else {
        float invl[4];
        #pragma unroll
        for (int r = 0; r < 4; ++r) invl[r] = 1.0f / lrun[r];
        #pragma unroll
        for (int nt = 0; nt < 8; ++nt)
            #pragma unroll
            for (int r = 0; r < 4; ++r)
                out[((size_t)b * T_SEQ + qrow0 + quad * 4 + r) * H_DIM + nt * 16 + l15]
                    = accO[nt][r] * invl[r];
    }
}

// ---------------------------------------------------------------------------
// combine: out = (sum_c pO[c]) / (sum_c l[c]); nc = qt/8+1 in 2..4. (unchanged)
// ---------------------------------------------------------------------------
__global__ __launch_bounds__(256) void attn_combine(
    const _Float16* __restrict__ pO, const float* __restrict__ ml,
    float* __restrict__ out)
{
    const int n  = blockIdx.x;
    const int b  = n & 7;
    const int m  = n >> 3;               // 0..95
    const int rg = m & 3;
    const int qt = 8 + (m >> 2);         // 8..31
    const int nc = (qt >> 3) + 1;        // 2..4

    int u0 = 0;
    #pragma unroll 1
    for (int q2 = 31; q2 > qt; --q2) u0 += (q2 >> 3) + 1;
    const size_t pid0 = (size_t)b * 72 + u0;

    const int t   = threadIdx.x;
    const int row = rg * 16 + (t >> 4);
    const int h   = (t & 15) * 8;

    float lsum = 0.0f;
    #pragma unroll 1
    for (int c = 0; c < nc; ++c)
        lsum += ml[(pid0 + c) * 64 + row];

    float acc[8] = {};
    #pragma unroll 1
    for (int c = 0; c < nc; ++c) {
        half8 po = *(const half8*)(pO + (pid0 + c) * 8192 + row * 128 + h);
        #pragma unroll
        for (int j = 0; j < 8; ++j) acc[j] += (float)po[j];
    }

    const float inv = 1.0f / lsum;
    float* op = out + ((size_t)b * T_SEQ + qt * 64 + row) * H_DIM + h;
    f32x4 o0 = { acc[0] * inv, acc[1] * inv, acc[2] * inv, acc[3] * inv };
    f32x4 o1 = { acc[4] * inv, acc[5] * inv, acc[6] * inv, acc[7] * inv };
    *(f32x4*)(op)     = o0;
    *(f32x4*)(op + 4) = o1;
}

// ---------------------------------------------------------------------------
extern "C" void kernel_launch(void* const* d_in, const int* in_sizes, int n_in,
                              void* d_out, int out_size, void* d_ws, size_t ws_size,
                              hipStream_t stream)
{
    const float* x  = (const float*)d_in[0];
    const float* Wk = (const float*)d_in[1];
    const float* Wq = (const float*)d_in[2];
    const float* Wv = (const float*)d_in[3];
    float* out = (float*)d_out;

    _Float16* ws = (_Float16*)d_ws;
    const size_t NQKV = (size_t)B_SZ * T_SEQ * H_DIM;          // 2,097,152
    _Float16* q_ws  = ws;
    _Float16* k_ws  = ws + NQKV;
    _Float16* vT_ws = ws + 2 * NQKV;
    _Float16* wt_ws = ws + 3 * NQKV;                           // 3*C*H halfs
    _Float16* pO_ws = wt_ws + 3 * (size_t)(C_DIM * H_DIM);     // 576 units * 8192 halfs
    float*    ml_ws = (float*)(pO_ws + (size_t)576 * 8192);    // 576 * 64 floats

    prep_kernel <<<dim3(512, 3), 256, 0, stream>>>(Wk, Wq, Wv, wt_ws);
    proj_kernel <<<dim3(256, 3), 256, 0, stream>>>(x, wt_ws, q_ws, k_ws, vT_ws);
    attn_kernel <<<640, 256, 0, stream>>>(q_ws, k_ws, vT_ws, pO_ws, ml_ws, out);
    attn_combine<<<768, 256, 0, stream>>>(pO_ws, ml_ws, out);
}